// Round 1
// baseline (1524.290 us; speedup 1.0000x reference)
//
#include <hip/hip_runtime.h>
#include <math.h>

#define BATCH 512
#define DIM 256
#define HEADS 4
#define KD 16
#define VD 64
#define NQ 196          // 14*14
#define QKV_OUT 96
#define CHW (DIM * NQ)  // 50176

// LDS layout (floats)
#define FEAT_OFF 0            // feat/out: [64][196] = 12544
#define QRAW_OFF 12544        // qraw:     [16][196] = 3136
#define QC_OFF   15680        // qc:       [196][16] = 3136
#define KB_OFF   18816        // kb:       [196][16] = 3136
#define VB_OFF   21952        // vb:       [196][64] = 12544
#define SMEM_FLOATS 34496     // *4 = 137984 bytes (gfx950 LDS max 160 KiB)

// -------------------- kernel 0: expand relative-position bias --------------------
__global__ __launch_bounds__(256)
void bias_expand_kernel(const float* __restrict__ attn_biases,
                        const int* __restrict__ bias_idxs,
                        float* __restrict__ biasg) {
    int i = blockIdx.x * 256 + threadIdx.x;
    const int total = HEADS * NQ * NQ;
    if (i < total) {
        int h = i / (NQ * NQ);
        int r = i - h * (NQ * NQ);
        biasg[i] = attn_biases[h * NQ + bias_idxs[r]];
    }
}

// -------------------- kernel 1: fused cascaded attention (per-sample block) ------
__global__ __launch_bounds__(256, 1)
void cascade_attn_kernel(const float* __restrict__ x,
                         const float* __restrict__ qkv_w,
                         const float* __restrict__ qkv_g,
                         const float* __restrict__ qkv_b,
                         const float* __restrict__ qkv_rm,
                         const float* __restrict__ qkv_rv,
                         const float* __restrict__ dw_w,
                         const float* __restrict__ dw_g,
                         const float* __restrict__ dw_b,
                         const float* __restrict__ dw_rm,
                         const float* __restrict__ dw_rv,
                         const float* __restrict__ biasg,
                         float* __restrict__ yrelu) {
    extern __shared__ __align__(16) float smem[];
    float* feat = smem + FEAT_OFF;   // [c][n]
    float* qraw = smem + QRAW_OFF;   // [c][n]
    float* qc   = smem + QC_OFF;     // [n][d]  (conv output, *0.25 folded)
    float* kb   = smem + KB_OFF;     // [n][d]
    float* vb   = smem + VB_OFF;     // [n][d]

    const int b = blockIdx.x;
    const int tid = threadIdx.x;
    const float* xb = x + (size_t)b * CHW;

    // init feat = chunk 0
    for (int i = tid; i < VD * NQ; i += 256) feat[i] = xb[i];
    __syncthreads();

    for (int h = 0; h < HEADS; ++h) {
        // ---- phase A: cascade add (h>0): feat = prev_out + chunk[h] ----
        if (h > 0) {
            const float* xc = xb + h * VD * NQ;
            for (int i = tid; i < VD * NQ; i += 256) feat[i] += xc[i];
            __syncthreads();
        }

        // ---- phase B: qkv matmul (96x64 @ 64x196) with folded BN ----
        const float* wq = qkv_w + h * QKV_OUT * 64;
        for (int task = tid; task < 24 * 49; task += 256) {
            int og = task / 49;
            int ng = task - og * 49;
            int o0 = og * 4, n0 = ng * 4;
            float acc[4][4] = {{0.f,0.f,0.f,0.f},{0.f,0.f,0.f,0.f},
                               {0.f,0.f,0.f,0.f},{0.f,0.f,0.f,0.f}};
            for (int c4 = 0; c4 < 16; ++c4) {
                float fr[16];
                #pragma unroll
                for (int cc = 0; cc < 4; ++cc)
                    *(float4*)&fr[cc * 4] = *(const float4*)&feat[(c4 * 4 + cc) * NQ + n0];
                float wr[16];
                #pragma unroll
                for (int j = 0; j < 4; ++j)
                    *(float4*)&wr[j * 4] = *(const float4*)&wq[(o0 + j) * 64 + c4 * 4];
                #pragma unroll
                for (int j = 0; j < 4; ++j)
                    #pragma unroll
                    for (int cc = 0; cc < 4; ++cc)
                        #pragma unroll
                        for (int i = 0; i < 4; ++i)
                            acc[j][i] = fmaf(wr[j * 4 + cc], fr[cc * 4 + i], acc[j][i]);
            }
            #pragma unroll
            for (int j = 0; j < 4; ++j) {
                int o = o0 + j;
                float s = qkv_g[h * 96 + o] * rsqrtf(qkv_rv[h * 96 + o] + 1e-5f);
                float t = qkv_b[h * 96 + o] - qkv_rm[h * 96 + o] * s;
                float r0 = fmaf(acc[j][0], s, t);
                float r1 = fmaf(acc[j][1], s, t);
                float r2 = fmaf(acc[j][2], s, t);
                float r3 = fmaf(acc[j][3], s, t);
                if (o < KD) {
                    *(float4*)&qraw[o * NQ + n0] = make_float4(r0, r1, r2, r3);
                } else if (o < 2 * KD) {
                    int ko = o - KD;
                    kb[(n0 + 0) * KD + ko] = r0;
                    kb[(n0 + 1) * KD + ko] = r1;
                    kb[(n0 + 2) * KD + ko] = r2;
                    kb[(n0 + 3) * KD + ko] = r3;
                } else {
                    int vo = o - 2 * KD;
                    vb[(n0 + 0) * VD + vo] = r0;
                    vb[(n0 + 1) * VD + vo] = r1;
                    vb[(n0 + 2) * VD + vo] = r2;
                    vb[(n0 + 3) * VD + vo] = r3;
                }
            }
        }
        __syncthreads();

        // ---- phase C: depthwise 5x5 conv on q (pad 2) + folded BN + *scale ----
        const float* wd = dw_w + h * KD * 25;
        for (int task = tid; task < KD * NQ; task += 256) {
            int c = task / NQ;
            int n = task - c * NQ;
            int py = n / 14, px = n - py * 14;
            float acc = 0.f;
            #pragma unroll
            for (int ky = 0; ky < 5; ++ky) {
                int yy = py + ky - 2;
                if (yy < 0 || yy >= 14) continue;
                #pragma unroll
                for (int kx = 0; kx < 5; ++kx) {
                    int xx = px + kx - 2;
                    if (xx < 0 || xx >= 14) continue;
                    acc = fmaf(wd[c * 25 + ky * 5 + kx], qraw[c * NQ + yy * 14 + xx], acc);
                }
            }
            float s = dw_g[h * KD + c] * rsqrtf(dw_rv[h * KD + c] + 1e-5f);
            float t = dw_b[h * KD + c] - dw_rm[h * KD + c] * s;
            qc[n * KD + c] = fmaf(acc, s, t) * 0.25f;  // scale = KD^-0.5
        }
        __syncthreads();

        // ---- phase D: attention (two-pass softmax), one query per thread ----
        const float* bh = biasg + h * NQ * NQ;  // symmetric: bh[m*196+n] == bias[n][m]
        if (tid < NQ) {
            int n = tid;
            float qr[16];
            #pragma unroll
            for (int d = 0; d < 16; ++d) qr[d] = qc[n * KD + d];

            // pass 1: row max
            float mx = -1e30f;
            {
                float bnext = bh[n];
                for (int m = 0; m < NQ; ++m) {
                    float bcur = bnext;
                    if (m + 1 < NQ) bnext = bh[(m + 1) * NQ + n];
                    float kk[16];
                    #pragma unroll
                    for (int d4 = 0; d4 < 4; ++d4)
                        *(float4*)&kk[d4 * 4] = *(const float4*)&kb[m * KD + d4 * 4];
                    float p0 = 0.f, p1 = 0.f, p2 = 0.f, p3 = 0.f;
                    #pragma unroll
                    for (int d = 0; d < 16; d += 4) {
                        p0 = fmaf(qr[d + 0], kk[d + 0], p0);
                        p1 = fmaf(qr[d + 1], kk[d + 1], p1);
                        p2 = fmaf(qr[d + 2], kk[d + 2], p2);
                        p3 = fmaf(qr[d + 3], kk[d + 3], p3);
                    }
                    float sc = (p0 + p1) + (p2 + p3) + bcur;
                    mx = fmaxf(mx, sc);
                }
            }
            // pass 2: exp + PV accumulate
            float den = 0.f;
            float out[VD];
            #pragma unroll
            for (int d = 0; d < VD; ++d) out[d] = 0.f;
            {
                float bnext = bh[n];
                for (int m = 0; m < NQ; ++m) {
                    float bcur = bnext;
                    if (m + 1 < NQ) bnext = bh[(m + 1) * NQ + n];
                    float kk[16];
                    #pragma unroll
                    for (int d4 = 0; d4 < 4; ++d4)
                        *(float4*)&kk[d4 * 4] = *(const float4*)&kb[m * KD + d4 * 4];
                    float p0 = 0.f, p1 = 0.f, p2 = 0.f, p3 = 0.f;
                    #pragma unroll
                    for (int d = 0; d < 16; d += 4) {
                        p0 = fmaf(qr[d + 0], kk[d + 0], p0);
                        p1 = fmaf(qr[d + 1], kk[d + 1], p1);
                        p2 = fmaf(qr[d + 2], kk[d + 2], p2);
                        p3 = fmaf(qr[d + 3], kk[d + 3], p3);
                    }
                    float sc = (p0 + p1) + (p2 + p3) + bcur;
                    float e = __expf(sc - mx);
                    den += e;
                    #pragma unroll
                    for (int d4 = 0; d4 < 16; ++d4) {
                        float4 v4 = *(const float4*)&vb[m * VD + d4 * 4];
                        out[d4 * 4 + 0] = fmaf(e, v4.x, out[d4 * 4 + 0]);
                        out[d4 * 4 + 1] = fmaf(e, v4.y, out[d4 * 4 + 1]);
                        out[d4 * 4 + 2] = fmaf(e, v4.z, out[d4 * 4 + 2]);
                        out[d4 * 4 + 3] = fmaf(e, v4.w, out[d4 * 4 + 3]);
                    }
                }
            }
            float inv = 1.0f / den;
            float* yg = yrelu + ((size_t)b * DIM + (size_t)h * VD) * NQ + n;
            #pragma unroll
            for (int d = 0; d < VD; ++d) {
                float val = out[d] * inv;
                feat[d * NQ + n] = val;            // pre-relu: cascade input for h+1
                yg[d * NQ] = fmaxf(val, 0.f);      // relu'd: proj input
            }
        }
        __syncthreads();
    }
}

// -------------------- kernel 2: projection GEMM (256x256) + folded BN ------------
__global__ __launch_bounds__(256)
void proj_kernel(const float* __restrict__ X,   // yrelu: [B][256][196]
                 const float* __restrict__ W,   // [256][256] row-major (o,c)
                 const float* __restrict__ pg,
                 const float* __restrict__ pb,
                 const float* __restrict__ prm,
                 const float* __restrict__ prv,
                 float* __restrict__ out) {
    __shared__ float Wt[16 * 64];    // [k][o]
    __shared__ float Xt[16 * 128];   // [k][j]
    const int tid = threadIdx.x;
    const int jt0 = blockIdx.x * 128;
    const int o0 = blockIdx.y * 64;
    const int ty = tid >> 4;        // 0..15 -> 4 o's each
    const int tx = tid & 15;        // 0..15 -> 8 j's each
    float acc[4][8];
    #pragma unroll
    for (int i = 0; i < 4; ++i)
        #pragma unroll
        for (int j = 0; j < 8; ++j) acc[i][j] = 0.f;

    for (int kt = 0; kt < 256; kt += 16) {
        {   // stage W tile (transposed)
            int o = tid >> 2;
            int kq = (tid & 3) * 4;
            float4 w4 = *(const float4*)&W[(o0 + o) * 256 + kt + kq];
            Wt[(kq + 0) * 64 + o] = w4.x;
            Wt[(kq + 1) * 64 + o] = w4.y;
            Wt[(kq + 2) * 64 + o] = w4.z;
            Wt[(kq + 3) * 64 + o] = w4.w;
        }
        #pragma unroll
        for (int i = 0; i < 8; ++i) {  // stage X tile
            int idx = tid + i * 256;
            int k = idx >> 7;
            int jj = idx & 127;
            int j = jt0 + jj;
            int bb = j / NQ;
            int n = j - bb * NQ;
            Xt[k * 128 + jj] = X[(size_t)bb * CHW + (size_t)(kt + k) * NQ + n];
        }
        __syncthreads();
        #pragma unroll
        for (int k = 0; k < 16; ++k) {
            float a[4];
            *(float4*)a = *(const float4*)&Wt[k * 64 + ty * 4];
            float bv[8];
            *(float4*)&bv[0] = *(const float4*)&Xt[k * 128 + tx * 8];
            *(float4*)&bv[4] = *(const float4*)&Xt[k * 128 + tx * 8 + 4];
            #pragma unroll
            for (int i = 0; i < 4; ++i)
                #pragma unroll
                for (int j = 0; j < 8; ++j)
                    acc[i][j] = fmaf(a[i], bv[j], acc[i][j]);
        }
        __syncthreads();
    }
    #pragma unroll
    for (int i = 0; i < 4; ++i) {
        int o = o0 + ty * 4 + i;
        float s = pg[o] * rsqrtf(prv[o] + 1e-5f);
        float t = pb[o] - prm[o] * s;
        #pragma unroll
        for (int j = 0; j < 8; ++j) {
            int jq = jt0 + tx * 8 + j;
            int bb = jq / NQ;
            int n = jq - bb * NQ;
            out[(size_t)bb * CHW + (size_t)o * NQ + n] = fmaf(acc[i][j], s, t);
        }
    }
}

// -------------------- launch --------------------
extern "C" void kernel_launch(void* const* d_in, const int* in_sizes, int n_in,
                              void* d_out, int out_size, void* d_ws, size_t ws_size,
                              hipStream_t stream) {
    const float* x        = (const float*)d_in[0];
    const float* qkv_w    = (const float*)d_in[1];
    const float* qkv_g    = (const float*)d_in[2];
    const float* qkv_b    = (const float*)d_in[3];
    const float* qkv_rm   = (const float*)d_in[4];
    const float* qkv_rv   = (const float*)d_in[5];
    const float* dw_w     = (const float*)d_in[6];
    const float* dw_g     = (const float*)d_in[7];
    const float* dw_b     = (const float*)d_in[8];
    const float* dw_rm    = (const float*)d_in[9];
    const float* dw_rv    = (const float*)d_in[10];
    const float* proj_w   = (const float*)d_in[11];
    const float* proj_g   = (const float*)d_in[12];
    const float* proj_b   = (const float*)d_in[13];
    const float* proj_rm  = (const float*)d_in[14];
    const float* proj_rv  = (const float*)d_in[15];
    const float* attn_bs  = (const float*)d_in[16];
    const int*   bias_idx = (const int*)d_in[17];

    float* wsf   = (float*)d_ws;
    float* biasg = wsf;                       // HEADS*NQ*NQ = 153664 floats
    float* yrelu = wsf + HEADS * NQ * NQ;     // B*DIM*NQ = 25690112 floats

    // 0) expand relative-position bias (symmetric in n,m)
    {
        int total = HEADS * NQ * NQ;
        hipLaunchKernelGGL(bias_expand_kernel, dim3((total + 255) / 256), dim3(256),
                           0, stream, attn_bs, bias_idx, biasg);
    }
    // 1) fused cascade: qkv + dwconv + attention, writes relu'd heads to yrelu
    hipLaunchKernelGGL(cascade_attn_kernel, dim3(BATCH), dim3(256),
                       SMEM_FLOATS * sizeof(float), stream,
                       x, qkv_w, qkv_g, qkv_b, qkv_rm, qkv_rv,
                       dw_w, dw_g, dw_b, dw_rm, dw_rv, biasg, yrelu);
    // 2) projection GEMM + BN
    hipLaunchKernelGGL(proj_kernel, dim3(784, 4), dim3(256), 0, stream,
                       yrelu, proj_w, proj_g, proj_b, proj_rm, proj_rv,
                       (float*)d_out);
}

// Round 2
// 1217.973 us; speedup vs baseline: 1.2515x; 1.2515x over previous
//
#include <hip/hip_runtime.h>
#include <math.h>

#define BATCH 512
#define DIM 256
#define HEADS 4
#define KD 16
#define VD 64
#define NQ 196          // 14*14
#define QKV_OUT 96
#define CHW (DIM * NQ)  // 50176

// LDS layout (floats). Padded rows: kb/qc 16->20, vb 64->68 (16B-aligned rows).
#define FEAT_OFF 0            // feat/out: [64][196]  = 12544
#define QRAW_OFF 12544        // qraw:     [16][196]  = 3136
#define QC_OFF   15680        // qc:       [196][20]  = 3920
#define KB_OFF   19600        // kb:       [196][20]  = 3920
#define VB_OFF   23520        // vb:       [196][68]  = 13328
#define SMEM_FLOATS 36848     // *4 = 147392 bytes (< 160 KiB)

// -------------------- kernel 0: expand relative-position bias --------------------
// bias_idxs is symmetric in (m,n), so biasg[h][n*196+m] == biasg[h][m*196+n].
__global__ __launch_bounds__(256)
void bias_expand_kernel(const float* __restrict__ attn_biases,
                        const int* __restrict__ bias_idxs,
                        float* __restrict__ biasg) {
    int i = blockIdx.x * 256 + threadIdx.x;
    const int total = HEADS * NQ * NQ;
    if (i < total) {
        int h = i / (NQ * NQ);
        int r = i - h * (NQ * NQ);
        biasg[i] = attn_biases[h * NQ + bias_idxs[r]];
    }
}

// -------------------- kernel 1: fused cascaded attention (per-sample block) ------
// 1024 threads = 16 waves (4/SIMD). LDS 147 KB -> 1 block/CU, 50% occupancy.
__global__ __launch_bounds__(1024, 4)
void cascade_attn_kernel(const float* __restrict__ x,
                         const float* __restrict__ qkv_w,
                         const float* __restrict__ qkv_g,
                         const float* __restrict__ qkv_b,
                         const float* __restrict__ qkv_rm,
                         const float* __restrict__ qkv_rv,
                         const float* __restrict__ dw_w,
                         const float* __restrict__ dw_g,
                         const float* __restrict__ dw_b,
                         const float* __restrict__ dw_rm,
                         const float* __restrict__ dw_rv,
                         const float* __restrict__ biasg,
                         float* __restrict__ yrelu) {
    extern __shared__ __align__(16) float smem[];
    float* feat = smem + FEAT_OFF;   // [c][196]
    float* qraw = smem + QRAW_OFF;   // [c][196]
    float* qc   = smem + QC_OFF;     // [n][20]
    float* kb   = smem + KB_OFF;     // [n][20]
    float* vb   = smem + VB_OFF;     // [n][68]

    const int b = blockIdx.x;
    const int tid = threadIdx.x;
    const float* xb = x + (size_t)b * CHW;

    for (int i = tid; i < VD * NQ; i += 1024) feat[i] = xb[i];
    __syncthreads();

    for (int h = 0; h < HEADS; ++h) {
        // ---- phase A: cascade add (h>0): feat += chunk[h] ----
        if (h > 0) {
            const float* xc = xb + h * VD * NQ;
            for (int i = tid; i < VD * NQ; i += 1024) feat[i] += xc[i];
            __syncthreads();
        }

        // ---- phase B: qkv matmul (96x64 @ 64x196), folded BN, 4o x 4n tiles ----
        const float* wq = qkv_w + h * QKV_OUT * 64;
        for (int task = tid; task < 24 * 49; task += 1024) {
            int og = task / 49;
            int ng = task - og * 49;
            int o0 = og * 4, n0 = ng * 4;
            float acc[4][4] = {{0.f,0.f,0.f,0.f},{0.f,0.f,0.f,0.f},
                               {0.f,0.f,0.f,0.f},{0.f,0.f,0.f,0.f}};
            for (int c4 = 0; c4 < 16; ++c4) {
                float fr[16];
                #pragma unroll
                for (int cc = 0; cc < 4; ++cc)
                    *(float4*)&fr[cc * 4] = *(const float4*)&feat[(c4 * 4 + cc) * NQ + n0];
                float wr[16];
                #pragma unroll
                for (int j = 0; j < 4; ++j)
                    *(float4*)&wr[j * 4] = *(const float4*)&wq[(o0 + j) * 64 + c4 * 4];
                #pragma unroll
                for (int j = 0; j < 4; ++j)
                    #pragma unroll
                    for (int cc = 0; cc < 4; ++cc)
                        #pragma unroll
                        for (int i = 0; i < 4; ++i)
                            acc[j][i] = fmaf(wr[j * 4 + cc], fr[cc * 4 + i], acc[j][i]);
            }
            #pragma unroll
            for (int j = 0; j < 4; ++j) {
                int o = o0 + j;
                float s = qkv_g[h * 96 + o] * rsqrtf(qkv_rv[h * 96 + o] + 1e-5f);
                float t = qkv_b[h * 96 + o] - qkv_rm[h * 96 + o] * s;
                float r0 = fmaf(acc[j][0], s, t);
                float r1 = fmaf(acc[j][1], s, t);
                float r2 = fmaf(acc[j][2], s, t);
                float r3 = fmaf(acc[j][3], s, t);
                if (o < KD) {
                    *(float4*)&qraw[o * NQ + n0] = make_float4(r0, r1, r2, r3);
                } else if (o < 2 * KD) {
                    int ko = o - KD;
                    kb[(n0 + 0) * 20 + ko] = r0;
                    kb[(n0 + 1) * 20 + ko] = r1;
                    kb[(n0 + 2) * 20 + ko] = r2;
                    kb[(n0 + 3) * 20 + ko] = r3;
                } else {
                    int vo = o - 2 * KD;
                    vb[(n0 + 0) * 68 + vo] = r0;
                    vb[(n0 + 1) * 68 + vo] = r1;
                    vb[(n0 + 2) * 68 + vo] = r2;
                    vb[(n0 + 3) * 68 + vo] = r3;
                }
            }
        }
        __syncthreads();

        // ---- phase C: depthwise 5x5 conv on q + folded BN + *scale ----
        const float* wd = dw_w + h * KD * 25;
        for (int task = tid; task < KD * NQ; task += 1024) {
            int c = task / NQ;
            int n = task - c * NQ;
            int py = n / 14, px = n - py * 14;
            float acc = 0.f;
            #pragma unroll
            for (int ky = 0; ky < 5; ++ky) {
                int yy = py + ky - 2;
                if (yy < 0 || yy >= 14) continue;
                #pragma unroll
                for (int kx = 0; kx < 5; ++kx) {
                    int xx = px + kx - 2;
                    if (xx < 0 || xx >= 14) continue;
                    acc = fmaf(wd[c * 25 + ky * 5 + kx], qraw[c * NQ + yy * 14 + xx], acc);
                }
            }
            float s = dw_g[h * KD + c] * rsqrtf(dw_rv[h * KD + c] + 1e-5f);
            float t = dw_b[h * KD + c] - dw_rm[h * KD + c] * s;
            qc[n * 20 + c] = fmaf(acc, s, t) * 0.25f;  // scale = KD^-0.5
        }
        __syncthreads();

        // ---- phase D: attention, single-pass softmax (scores bounded ~|3|) ----
        // thread = (d-quarter dq, query n). All lanes of a wave share dq -> kb/vb
        // reads are wave-broadcast (bank-free). QK recomputed per dq (cheap).
        {
            int dq = tid >> 8;       // 0..3
            int n  = tid & 255;      // query, active if < 196
            if (n < NQ) {
                float qr[16];
                #pragma unroll
                for (int i = 0; i < 4; ++i)
                    *(float4*)&qr[i * 4] = *(const float4*)&qc[n * 20 + i * 4];
                const float* bh = biasg + h * NQ * NQ + n;
                float den = 0.f;
                float out[16];
                #pragma unroll
                for (int i = 0; i < 16; ++i) out[i] = 0.f;
                float bnext = bh[0];
                const float* vrow = vb + dq * 16;
                for (int m = 0; m < NQ; ++m) {
                    float bcur = bnext;
                    if (m + 1 < NQ) bnext = bh[(m + 1) * NQ];
                    float kk[16];
                    #pragma unroll
                    for (int i = 0; i < 4; ++i)
                        *(float4*)&kk[i * 4] = *(const float4*)&kb[m * 20 + i * 4];
                    float vv[16];
                    #pragma unroll
                    for (int i = 0; i < 4; ++i)
                        *(float4*)&vv[i * 4] = *(const float4*)&vrow[m * 68 + i * 4];
                    float p0 = 0.f, p1 = 0.f, p2 = 0.f, p3 = 0.f;
                    #pragma unroll
                    for (int d = 0; d < 16; d += 4) {
                        p0 = fmaf(qr[d + 0], kk[d + 0], p0);
                        p1 = fmaf(qr[d + 1], kk[d + 1], p1);
                        p2 = fmaf(qr[d + 2], kk[d + 2], p2);
                        p3 = fmaf(qr[d + 3], kk[d + 3], p3);
                    }
                    float sc = (p0 + p1) + (p2 + p3) + bcur;
                    float e = __expf(sc);
                    den += e;
                    #pragma unroll
                    for (int i = 0; i < 16; ++i)
                        out[i] = fmaf(e, vv[i], out[i]);
                }
                float inv = 1.0f / den;
                float* yg = yrelu + ((size_t)b * DIM + (size_t)(h * VD + dq * 16)) * NQ + n;
                #pragma unroll
                for (int i = 0; i < 16; ++i) {
                    float val = out[i] * inv;
                    feat[(dq * 16 + i) * NQ + n] = val;   // cascade input for h+1
                    yg[i * NQ] = fmaxf(val, 0.f);         // relu'd: proj input
                }
            }
            __syncthreads();
        }
    }
}

// -------------------- kernel 2: projection GEMM (256x256) + folded BN ------------
// 512 threads, output tile 128o x 256j, 8x8 per-thread acc (VALU-bound ratio).
__global__ __launch_bounds__(512)
void proj_kernel(const float* __restrict__ X,   // yrelu: [B][256][196]
                 const float* __restrict__ W,   // [256][256] (o,c)
                 const float* __restrict__ pg,
                 const float* __restrict__ pb,
                 const float* __restrict__ prm,
                 const float* __restrict__ prv,
                 float* __restrict__ out) {
    __shared__ float Wt[16 * 132];   // [k][o], pad 128->132
    __shared__ float Xt[16 * 260];   // [k][j], pad 256->260
    const int tid = threadIdx.x;
    const int jt0 = blockIdx.x * 256;
    const int o0 = blockIdx.y * 128;
    const int og = tid >> 5;   // 0..15 -> 8 o's each
    const int jg = tid & 31;   // 0..31 -> 8 j's each
    float acc[8][8];
    #pragma unroll
    for (int i = 0; i < 8; ++i)
        #pragma unroll
        for (int j = 0; j < 8; ++j) acc[i][j] = 0.f;

    for (int kt = 0; kt < 256; kt += 16) {
        {   // stage W tile transposed: [k][o]
            int o = tid >> 2;
            int kq = (tid & 3) * 4;
            float4 w4 = *(const float4*)&W[(o0 + o) * 256 + kt + kq];
            Wt[(kq + 0) * 132 + o] = w4.x;
            Wt[(kq + 1) * 132 + o] = w4.y;
            Wt[(kq + 2) * 132 + o] = w4.z;
            Wt[(kq + 3) * 132 + o] = w4.w;
        }
        #pragma unroll
        for (int i = 0; i < 8; ++i) {  // stage X tile: 16k x 256j
            int idx = tid + i * 512;
            int k = idx >> 8;
            int jj = idx & 255;
            int j = jt0 + jj;
            int bb = j / NQ;
            int nn = j - bb * NQ;
            Xt[k * 260 + jj] = X[(size_t)bb * CHW + (size_t)(kt + k) * NQ + nn];
        }
        __syncthreads();
        #pragma unroll
        for (int k = 0; k < 16; ++k) {
            float a[8];
            *(float4*)&a[0] = *(const float4*)&Wt[k * 132 + og * 8];
            *(float4*)&a[4] = *(const float4*)&Wt[k * 132 + og * 8 + 4];
            float bv[8];
            *(float4*)&bv[0] = *(const float4*)&Xt[k * 260 + jg * 8];
            *(float4*)&bv[4] = *(const float4*)&Xt[k * 260 + jg * 8 + 4];
            #pragma unroll
            for (int i = 0; i < 8; ++i)
                #pragma unroll
                for (int j = 0; j < 8; ++j)
                    acc[i][j] = fmaf(a[i], bv[j], acc[i][j]);
        }
        __syncthreads();
    }
    #pragma unroll
    for (int i = 0; i < 8; ++i) {
        int o = o0 + og * 8 + i;
        float s = pg[o] * rsqrtf(prv[o] + 1e-5f);
        float t = pb[o] - prm[o] * s;
        #pragma unroll
        for (int j = 0; j < 8; ++j) {
            int jq = jt0 + jg * 8 + j;
            int bb = jq / NQ;
            int nn = jq - bb * NQ;
            out[(size_t)bb * CHW + (size_t)o * NQ + nn] = fmaf(acc[i][j], s, t);
        }
    }
}

// -------------------- launch --------------------
extern "C" void kernel_launch(void* const* d_in, const int* in_sizes, int n_in,
                              void* d_out, int out_size, void* d_ws, size_t ws_size,
                              hipStream_t stream) {
    const float* x        = (const float*)d_in[0];
    const float* qkv_w    = (const float*)d_in[1];
    const float* qkv_g    = (const float*)d_in[2];
    const float* qkv_b    = (const float*)d_in[3];
    const float* qkv_rm   = (const float*)d_in[4];
    const float* qkv_rv   = (const float*)d_in[5];
    const float* dw_w     = (const float*)d_in[6];
    const float* dw_g     = (const float*)d_in[7];
    const float* dw_b     = (const float*)d_in[8];
    const float* dw_rm    = (const float*)d_in[9];
    const float* dw_rv    = (const float*)d_in[10];
    const float* proj_w   = (const float*)d_in[11];
    const float* proj_g   = (const float*)d_in[12];
    const float* proj_b   = (const float*)d_in[13];
    const float* proj_rm  = (const float*)d_in[14];
    const float* proj_rv  = (const float*)d_in[15];
    const float* attn_bs  = (const float*)d_in[16];
    const int*   bias_idx = (const int*)d_in[17];

    float* wsf   = (float*)d_ws;
    float* biasg = wsf;                       // HEADS*NQ*NQ floats
    float* yrelu = wsf + HEADS * NQ * NQ;     // B*DIM*NQ floats

    {
        int total = HEADS * NQ * NQ;
        hipLaunchKernelGGL(bias_expand_kernel, dim3((total + 255) / 256), dim3(256),
                           0, stream, attn_bs, bias_idx, biasg);
    }
    hipLaunchKernelGGL(cascade_attn_kernel, dim3(BATCH), dim3(1024),
                       SMEM_FLOATS * sizeof(float), stream,
                       x, qkv_w, qkv_g, qkv_b, qkv_rm, qkv_rv,
                       dw_w, dw_g, dw_b, dw_rm, dw_rv, biasg, yrelu);
    hipLaunchKernelGGL(proj_kernel, dim3(392, 2), dim3(512), 0, stream,
                       yrelu, proj_w, proj_g, proj_b, proj_rm, proj_rv,
                       (float*)d_out);
}

// Round 3
// 700.521 us; speedup vs baseline: 2.1759x; 1.7387x over previous
//
#include <hip/hip_runtime.h>
#include <math.h>

#define BATCH 512
#define DIM 256
#define HEADS 4
#define KD 16
#define VD 64
#define NQ 196
#define CHW (DIM * NQ)   // 50176

typedef __attribute__((ext_vector_type(8))) short short8;
typedef __attribute__((ext_vector_type(4))) float f32x4;

#define MFMA16(A, B, C) __builtin_amdgcn_mfma_f32_16x16x32_bf16((A), (B), (C), 0, 0, 0)

__device__ __forceinline__ unsigned short f2bf(float f) {
    unsigned int u = __float_as_uint(f);
    u += 0x7FFFu + ((u >> 16) & 1u);          // round-to-nearest-even
    return (unsigned short)(u >> 16);
}
__device__ __forceinline__ float bf2f(unsigned short h) {
    return __uint_as_float(((unsigned int)h) << 16);
}
// load 8 consecutive floats, emit bf16 hi + lo-correction fragments
__device__ __forceinline__ void split8(const float* __restrict__ p, short8& hi, short8& lo) {
    float v[8];
    *(float4*)&v[0] = *(const float4*)p;
    *(float4*)&v[4] = *(const float4*)(p + 4);
    #pragma unroll
    for (int j = 0; j < 8; ++j) {
        unsigned short h = f2bf(v[j]);
        hi[j] = (short)h;
        lo[j] = (short)f2bf(v[j] - bf2f(h));
    }
}

// ---------------- LDS layout (bytes) ----------------
// union region: feat bf16 [208][72]  (29952 B)  OVERLAID BY  qc hi/lo [208][40] (33280 B)
#define OFF_QCH   0
#define OFF_QCL   16640
#define OFF_QRAW  33280      // fp32 [16][208] = 13312
#define OFF_KBH   46592      // bf16 [224][40] = 17920
#define OFF_KBL   64512
#define OFF_VBH   82432      // bf16 [64][232] = 29696
#define OFF_VBL   112128
#define OFF_P     141824     // bf16 [208][40] = 16640
#define OFF_DEN4  158464     // fp32 [208][4]  = 3328
#define OFF_SB    161792     // fp32 [96]
#define OFF_TB    162176     // fp32 [96]
#define OFF_DWS   162560     // fp32 [16]
#define OFF_DWT   162624     // fp32 [16]
#define SMEM_BYTES 162688    // <= 163840

// -------------------- kernel 0: expand relative-position bias --------------------
__global__ __launch_bounds__(256)
void bias_expand_kernel(const float* __restrict__ attn_biases,
                        const int* __restrict__ bias_idxs,
                        float* __restrict__ biasg) {
    int i = blockIdx.x * 256 + threadIdx.x;
    const int total = HEADS * NQ * NQ;
    if (i < total) {
        int h = i / (NQ * NQ);
        int r = i - h * (NQ * NQ);
        biasg[i] = attn_biases[h * NQ + bias_idxs[r]];
    }
}

// -------------------- kernel 1: fused cascaded attention, MFMA --------------------
__global__ __launch_bounds__(1024, 4)
void cascade_attn_kernel(const float* __restrict__ x,
                         const float* __restrict__ qkv_w,
                         const float* __restrict__ qkv_g,
                         const float* __restrict__ qkv_b,
                         const float* __restrict__ qkv_rm,
                         const float* __restrict__ qkv_rv,
                         const float* __restrict__ dw_w,
                         const float* __restrict__ dw_g,
                         const float* __restrict__ dw_b,
                         const float* __restrict__ dw_rm,
                         const float* __restrict__ dw_rv,
                         const float* __restrict__ biasg,
                         unsigned short* __restrict__ yrelu) {
    extern __shared__ __align__(16) char smem[];
    unsigned short* featU = (unsigned short*)(smem + OFF_QCH);  // [208][72] (overlaid by qc)
    unsigned short* qcH   = (unsigned short*)(smem + OFF_QCH);  // [208][40]
    unsigned short* qcL   = (unsigned short*)(smem + OFF_QCL);
    float*          qraw  = (float*)(smem + OFF_QRAW);          // [16][208]
    unsigned short* kbH   = (unsigned short*)(smem + OFF_KBH);  // [224][40]
    unsigned short* kbL   = (unsigned short*)(smem + OFF_KBL);
    unsigned short* vbH   = (unsigned short*)(smem + OFF_VBH);  // [64][232]
    unsigned short* vbL   = (unsigned short*)(smem + OFF_VBL);
    unsigned short* Pb    = (unsigned short*)(smem + OFF_P);    // [208][40]
    float*          den4  = (float*)(smem + OFF_DEN4);          // [208][4]
    float*          sbT   = (float*)(smem + OFF_SB);
    float*          tbT   = (float*)(smem + OFF_TB);
    float*          dwsT  = (float*)(smem + OFF_DWS);
    float*          dwtT  = (float*)(smem + OFF_DWT);

    const int b    = blockIdx.x;
    const int tid  = threadIdx.x;
    const int w    = tid >> 6;
    const int li   = tid & 15;
    const int quad = (tid >> 4) & 3;

    // ---- init: zero ALL of LDS (pads must be exactly 0 for MFMA k-padding) ----
    for (int t = tid; t < SMEM_BYTES / 4; t += 1024) ((unsigned int*)smem)[t] = 0u;
    __syncthreads();
    // feat = bf16(x chunk 0), layout [n][72c]
    for (int t = tid; t < VD * NQ; t += 1024) {
        int n = t % NQ, c = t / NQ;
        featU[n * 72 + c] = f2bf(x[((size_t)b * DIM + c) * NQ + n]);
    }
    __syncthreads();

    for (int h = 0; h < HEADS; ++h) {
        // ---- prologue: fold BN into (s,t) tables ----
        if (tid < 96) {
            float s = qkv_g[h * 96 + tid] * rsqrtf(qkv_rv[h * 96 + tid] + 1e-5f);
            sbT[tid] = s;
            tbT[tid] = qkv_b[h * 96 + tid] - qkv_rm[h * 96 + tid] * s;
        } else if (tid < 112) {
            int c = tid - 96;
            float s = dw_g[h * 16 + c] * rsqrtf(dw_rv[h * 16 + c] + 1e-5f);
            dwsT[c] = s;
            dwtT[c] = dw_b[h * 16 + c] - dw_rm[h * 16 + c] * s;
        }
        __syncthreads();

        // ---- phase B: QKV = W(hi+lo) x feat(bf16), MFMA, folded BN ----
        // tiles: 6 o-tiles x 13 n-tiles = 78
        for (int T = w; T < 78; T += 16) {
            int ot = T / 13, nt = T - ot * 13;
            const float* wrow = qkv_w + ((size_t)h * 96 + ot * 16 + li) * 64;
            short8 ah0, al0, ah1, al1;
            split8(wrow + quad * 8, ah0, al0);
            split8(wrow + 32 + quad * 8, ah1, al1);
            short8 b0 = *(const short8*)(featU + (nt * 16 + li) * 72 + quad * 8);
            short8 b1 = *(const short8*)(featU + (nt * 16 + li) * 72 + 32 + quad * 8);
            f32x4 acc = {0.f, 0.f, 0.f, 0.f};
            acc = MFMA16(ah0, b0, acc);
            acc = MFMA16(al0, b0, acc);
            acc = MFMA16(ah1, b1, acc);
            acc = MFMA16(al1, b1, acc);
            int n = nt * 16 + li;
            bool nok = (n < NQ);
            #pragma unroll
            for (int r = 0; r < 4; ++r) {
                int o = ot * 16 + quad * 4 + r;
                float val = acc[r] * sbT[o] + tbT[o];
                if (nok) {
                    if (o < 16) {
                        qraw[o * 208 + n] = val;
                    } else if (o < 32) {
                        int c = o - 16;
                        unsigned short hh = f2bf(val);
                        kbH[n * 40 + c] = hh;
                        kbL[n * 40 + c] = f2bf(val - bf2f(hh));
                    } else {
                        int d = o - 32;
                        unsigned short hh = f2bf(val);
                        vbH[d * 232 + n] = hh;
                        vbL[d * 232 + n] = f2bf(val - bf2f(hh));
                    }
                }
            }
        }
        __syncthreads();

        // ---- phase C: depthwise 5x5 conv + BN + *0.25, write qc hi/lo; zero pads ----
        for (int t = tid; t < KD * NQ; t += 1024) {
            int n = t % NQ, c = t / NQ;
            int py = n / 14, px = n - py * 14;
            const float* qr = qraw + c * 208;
            const float* wdc = dw_w + ((size_t)h * KD + c) * 25;
            float accv = 0.f;
            #pragma unroll
            for (int ky = 0; ky < 5; ++ky) {
                int yy = py + ky - 2;
                if (yy < 0 || yy >= 14) continue;
                #pragma unroll
                for (int kx = 0; kx < 5; ++kx) {
                    int xx = px + kx - 2;
                    if (xx < 0 || xx >= 14) continue;
                    accv = fmaf(wdc[ky * 5 + kx], qr[yy * 14 + xx], accv);
                }
            }
            float val = fmaf(accv, dwsT[c], dwtT[c]) * 0.25f;
            unsigned short hh = f2bf(val);
            qcH[n * 40 + c] = hh;
            qcL[n * 40 + c] = f2bf(val - bf2f(hh));
            // re-zero k-pad cols 16..31 (dirtied by feat overlay)
            qcH[n * 40 + 16 + c] = 0;
            qcL[n * 40 + 16 + c] = 0;
        }
        if (tid < 832) den4[tid] = 0.f;
        __syncthreads();

        // ---- phase D: attention. m-loop over 7 tiles of 32 keys ----
        f32x4 pacc[4];
        #pragma unroll
        for (int s = 0; s < 4; ++s) pacc[s] = (f32x4){0.f, 0.f, 0.f, 0.f};

        for (int mi = 0; mi < 7; ++mi) {
            // S-pass: 26 tiles (13 n-tiles x 2 m-subtiles); S = Q(hi+lo) x K(hi+lo), drop lo*lo
            for (int T = w; T < 26; T += 16) {
                int s = (T >= 13) ? 1 : 0;
                int nt = T - s * 13;
                int n0 = nt * 16;
                int mg = mi * 32 + s * 16 + li;       // global key index (= kb row)
                float bias4[4];
                #pragma unroll
                for (int r = 0; r < 4; ++r) {
                    int n = n0 + quad * 4 + r;
                    int ni = n < NQ ? n : NQ - 1;
                    int mgi = mg < NQ ? mg : NQ - 1;
                    bias4[r] = biasg[(size_t)h * (NQ * NQ) + ni * NQ + mgi];
                }
                short8 qh = *(const short8*)(qcH + (n0 + li) * 40 + quad * 8);
                short8 ql = *(const short8*)(qcL + (n0 + li) * 40 + quad * 8);
                short8 kh = *(const short8*)(kbH + mg * 40 + quad * 8);
                short8 kl = *(const short8*)(kbL + mg * 40 + quad * 8);
                f32x4 acc = {0.f, 0.f, 0.f, 0.f};
                acc = MFMA16(qh, kh, acc);
                acc = MFMA16(qh, kl, acc);
                acc = MFMA16(ql, kh, acc);
                bool mok = (mg < NQ);
                #pragma unroll
                for (int r = 0; r < 4; ++r) {
                    float e = mok ? __expf(acc[r] + bias4[r]) : 0.f;
                    int n = n0 + quad * 4 + r;
                    Pb[n * 40 + s * 16 + li] = f2bf(e);
                }
            }
            __syncthreads();

            // den-pass: accumulate row sums of the *bf16* P actually fed to MFMA
            if (tid < 832) {
                int n = tid >> 2, part = tid & 3;
                short8 pv = *(const short8*)(Pb + n * 40 + part * 8);
                float sum = 0.f;
                #pragma unroll
                for (int j = 0; j < 8; ++j) sum += bf2f((unsigned short)pv[j]);
                den4[n * 4 + part] += sum;
            }
            // PV: out += P x V(hi+lo); 52 tiles (13 n x 4 d), K=32 per m-iter
            {
                int slot = 0;
                for (int T = w; T < 52; T += 16, ++slot) {
                    int dt = T / 13, nt = T - dt * 13;
                    short8 p  = *(const short8*)(Pb + (nt * 16 + li) * 40 + quad * 8);
                    short8 vh = *(const short8*)(vbH + (dt * 16 + li) * 232 + mi * 32 + quad * 8);
                    short8 vl = *(const short8*)(vbL + (dt * 16 + li) * 232 + mi * 32 + quad * 8);
                    pacc[slot] = MFMA16(p, vh, pacc[slot]);
                    pacc[slot] = MFMA16(p, vl, pacc[slot]);
                }
            }
            __syncthreads();
        }

        // ---- PV epilogue: normalize, write new feat (bf16) ----
        {
            int slot = 0;
            for (int T = w; T < 52; T += 16, ++slot) {
                int dt = T / 13, nt = T - dt * 13;
                int d = dt * 16 + li;
                #pragma unroll
                for (int r = 0; r < 4; ++r) {
                    int n = nt * 16 + quad * 4 + r;
                    if (n < NQ) {
                        f32x4 dv = *(const f32x4*)(den4 + n * 4);
                        float dn = (dv.x + dv.y) + (dv.z + dv.w);
                        float val = pacc[slot][r] / dn;
                        featU[n * 72 + d] = f2bf(val);
                    }
                }
            }
        }
        __syncthreads();

        // ---- yrelu write (+ cascade add for next head) ----
        for (int t = tid; t < VD * NQ; t += 1024) {
            int n = t % NQ, c = t / NQ;
            unsigned short u = featU[n * 72 + c];
            unsigned short ru = (u & 0x8000u) ? (unsigned short)0 : u;
            yrelu[((size_t)b * DIM + h * VD + c) * NQ + n] = ru;
            if (h < 3) {
                float v = bf2f(u) + x[((size_t)b * DIM + (h + 1) * VD + c) * NQ + n];
                featU[n * 72 + c] = f2bf(v);
            }
        }
        if (h < 3) {
            // re-zero feat pad rows 196..207 (dirtied by qc overlay)
            for (int t = tid; t < 12 * 64; t += 1024)
                featU[(NQ + t / 64) * 72 + (t & 63)] = 0;
        }
        __syncthreads();
    }
}

// -------------------- kernel 2: projection GEMM (MFMA) + folded BN ----------------
// block: 512 thr (8 waves), tile 64o x 256j, K=256 in 8 steps of 32
__global__ __launch_bounds__(512, 4)
void proj_kernel(const unsigned short* __restrict__ X,  // yrelu bf16 [B][256][196]
                 const float* __restrict__ W,           // [256][256] (o,c)
                 const float* __restrict__ pg,
                 const float* __restrict__ pb,
                 const float* __restrict__ prm,
                 const float* __restrict__ prv,
                 float* __restrict__ out) {
    __shared__ __align__(16) unsigned short Xt[256 * 40];  // [j][40c] 20480 B
    const int tid  = threadIdx.x;
    const int w    = tid >> 6;
    const int li   = tid & 15;
    const int quad = (tid >> 4) & 3;
    const int jb   = blockIdx.x * 256;
    const int o0   = blockIdx.y * 64 + (w & 3) * 16;
    const int jt0  = (w >> 2) * 8;

    // precompute staging bases: element e = i*512 + tid -> (cl = e>>8, jj = e&255)
    int sbase[16];
    #pragma unroll
    for (int i = 0; i < 16; ++i) {
        int e = i * 512 + tid;
        int jj = e & 255;
        int j = jb + jj;
        int bb = j / NQ;
        sbase[i] = bb * CHW + (j - bb * NQ);
    }

    f32x4 acc[8];
    #pragma unroll
    for (int i = 0; i < 8; ++i) acc[i] = (f32x4){0.f, 0.f, 0.f, 0.f};

    for (int ks = 0; ks < 8; ++ks) {
        #pragma unroll
        for (int i = 0; i < 16; ++i) {
            int e = i * 512 + tid;
            int cl = e >> 8;
            int jj = e & 255;
            Xt[jj * 40 + cl] = X[sbase[i] + (size_t)(ks * 32 + cl) * NQ];
        }
        __syncthreads();
        const float* wrow = W + (o0 + li) * 256 + ks * 32;
        short8 ah, al;
        split8(wrow + quad * 8, ah, al);
        #pragma unroll
        for (int jt = 0; jt < 8; ++jt) {
            short8 bx = *(const short8*)(Xt + ((jt0 + jt) * 16 + li) * 40 + quad * 8);
            acc[jt] = MFMA16(ah, bx, acc[jt]);
            acc[jt] = MFMA16(al, bx, acc[jt]);
        }
        __syncthreads();
    }
    // epilogue: BN + store fp32
    #pragma unroll
    for (int r = 0; r < 4; ++r) {
        int o = o0 + quad * 4 + r;
        float s = pg[o] * rsqrtf(prv[o] + 1e-5f);
        float t = pb[o] - prm[o] * s;
        #pragma unroll
        for (int jt = 0; jt < 8; ++jt) {
            int j = jb + (jt0 + jt) * 16 + li;
            int bb = j / NQ;
            int n = j - bb * NQ;
            out[(size_t)bb * CHW + (size_t)o * NQ + n] = fmaf(acc[jt][r], s, t);
        }
    }
}

// -------------------- launch --------------------
extern "C" void kernel_launch(void* const* d_in, const int* in_sizes, int n_in,
                              void* d_out, int out_size, void* d_ws, size_t ws_size,
                              hipStream_t stream) {
    const float* x        = (const float*)d_in[0];
    const float* qkv_w    = (const float*)d_in[1];
    const float* qkv_g    = (const float*)d_in[2];
    const float* qkv_b    = (const float*)d_in[3];
    const float* qkv_rm   = (const float*)d_in[4];
    const float* qkv_rv   = (const float*)d_in[5];
    const float* dw_w     = (const float*)d_in[6];
    const float* dw_g     = (const float*)d_in[7];
    const float* dw_b     = (const float*)d_in[8];
    const float* dw_rm    = (const float*)d_in[9];
    const float* dw_rv    = (const float*)d_in[10];
    const float* proj_w   = (const float*)d_in[11];
    const float* proj_g   = (const float*)d_in[12];
    const float* proj_b   = (const float*)d_in[13];
    const float* proj_rm  = (const float*)d_in[14];
    const float* proj_rv  = (const float*)d_in[15];
    const float* attn_bs  = (const float*)d_in[16];
    const int*   bias_idx = (const int*)d_in[17];

    float* biasg = (float*)d_ws;                                   // 153664 fp32
    unsigned short* yrelu = (unsigned short*)((char*)d_ws + 614656); // B*DIM*NQ bf16

    {
        int total = HEADS * NQ * NQ;
        hipLaunchKernelGGL(bias_expand_kernel, dim3((total + 255) / 256), dim3(256),
                           0, stream, attn_bs, bias_idx, biasg);
    }
    hipLaunchKernelGGL(cascade_attn_kernel, dim3(BATCH), dim3(1024),
                       SMEM_BYTES, stream,
                       x, qkv_w, qkv_g, qkv_b, qkv_rm, qkv_rv,
                       dw_w, dw_g, dw_b, dw_rm, dw_rv, biasg, yrelu);
    hipLaunchKernelGGL(proj_kernel, dim3(392, 4), dim3(512), 0, stream,
                       yrelu, proj_w, proj_g, proj_b, proj_rm, proj_rv,
                       (float*)d_out);
}